// Round 5
// baseline (1895.358 us; speedup 1.0000x reference)
//
#include <hip/hip_runtime.h>
#include <math.h>

#define NTOK   256000
#define TOKB   16000
#define EPS    1e-5f

__device__ __forceinline__ float gelu_f(float x){
  return 0.5f*x*(1.0f+erff(x*0.70710678118654752440f));
}
__device__ __forceinline__ float elu1_f(float x){
  return x>0.0f ? x+1.0f : __expf(x);   // elu(x)+1
}

// ---------------------------------------------------------------------------
// Tokenizer: band conv(51) -> 1x1 conv(4->32) -> BN -> GELU -> avgpool(4)
// ---------------------------------------------------------------------------
__global__ __launch_bounds__(256) void k_tokenize(
    const float* __restrict__ x, const float* __restrict__ band_w,
    const float* __restrict__ pw_w, const float* __restrict__ bn_g,
    const float* __restrict__ bn_b, const float* __restrict__ bn_m,
    const float* __restrict__ bn_v, float* __restrict__ hout)
{
  __shared__ float sx[1050];
  __shared__ float sbw[4][51];
  __shared__ float spw[32][4];
  __shared__ float sscale[32], sshift[32];
  const int tid = threadIdx.x;
  const int b = blockIdx.x >> 6, e = blockIdx.x & 63;
  const float* xr = x + (size_t)(b*64 + e)*1000;
  for (int i=tid;i<1050;i+=256){ int t=i-25; sx[i]=(t>=0&&t<1000)?xr[t]:0.0f; }
  for (int i=tid;i<204;i+=256){ sbw[i/51][i%51] = band_w[i]; }
  for (int i=tid;i<128;i+=256){ spw[i>>2][i&3] = pw_w[i]; }
  if (tid<32){ float sc = bn_g[tid]*rsqrtf(bn_v[tid]+EPS);
               sscale[tid]=sc; sshift[tid]=bn_b[tid]-bn_m[tid]*sc; }
  __syncthreads();
  const int tp = tid;
  if (tp < 250) {
    float acc[32];
    #pragma unroll
    for (int o=0;o<32;o++) acc[o]=0.0f;
    for (int j=0;j<4;j++){
      const int t = 4*tp+j;
      float c0=0,c1=0,c2=0,c3=0;
      for (int k=0;k<51;k++){
        float xv = sx[t+k];
        c0 += xv*sbw[0][k]; c1 += xv*sbw[1][k];
        c2 += xv*sbw[2][k]; c3 += xv*sbw[3][k];
      }
      #pragma unroll
      for (int o=0;o<32;o++){
        float hv = spw[o][0]*c0 + spw[o][1]*c1 + spw[o][2]*c2 + spw[o][3]*c3;
        hv = hv*sscale[o] + sshift[o];
        acc[o] += gelu_f(hv);
      }
    }
    const int tok = b*TOKB + e*250 + tp;
    float4* dst = (float4*)(hout + (size_t)tok*32);
    #pragma unroll
    for (int o8=0;o8<8;o8++)
      dst[o8] = make_float4(acc[o8*4]*0.25f, acc[o8*4+1]*0.25f,
                            acc[o8*4+2]*0.25f, acc[o8*4+3]*0.25f);
  }
}

// ---------------------------------------------------------------------------
// Pass A: per 128-token tile: ln1 -> k,v -> K-features -> partial KV[h,f,d]
// ---------------------------------------------------------------------------
__global__ __launch_bounds__(256) void k_kv_partial(
    const float* __restrict__ hbuf, const float* __restrict__ ln1_g,
    const float* __restrict__ ln1_b, const float* __restrict__ wqkv,
    const float* __restrict__ proj_mat, float* __restrict__ kvpart, int l)
{
  __shared__ __align__(16) float sk[128][36];
  __shared__ __align__(16) float sv[128][36];
  __shared__ __align__(16) float swkT[64][32];   // [j][i]: j=0..31 k-cols, 32..63 v-cols
  __shared__ float sg[32], sb[32];
  const int tid = threadIdx.x;
  const float* W = wqkv + l*32*96;
  for (int idx=tid;idx<2048;idx+=256){
    int i = idx&31, j = idx>>5;
    swkT[j][i] = W[i*96 + 32 + j];
  }
  if (tid<32){ sg[tid]=ln1_g[l*32+tid]; sb[tid]=ln1_b[l*32+tid]; }
  __syncthreads();
  {
    const int tloc = tid>>1, half = tid&1;
    const int tok = blockIdx.x*128 + tloc;
    float hx[32];
    const float4* src = (const float4*)(hbuf + (size_t)tok*32);
    #pragma unroll
    for (int i=0;i<8;i++){ float4 v4=src[i]; hx[4*i]=v4.x; hx[4*i+1]=v4.y; hx[4*i+2]=v4.z; hx[4*i+3]=v4.w; }
    float mu=0;
    #pragma unroll
    for (int i=0;i<32;i++) mu += hx[i];
    mu *= (1.0f/32.0f);
    float vs=0;
    #pragma unroll
    for (int i=0;i<32;i++){ float d=hx[i]-mu; vs += d*d; }
    const float inv = rsqrtf(vs*(1.0f/32.0f)+EPS);
    float xn[32];
    #pragma unroll
    for (int i=0;i<32;i++) xn[i] = (hx[i]-mu)*inv*sg[i]+sb[i];
    const int j0 = half*16;
    #pragma unroll 4
    for (int jj=0;jj<16;jj++){
      const int j = j0+jj;
      const float4* wk4 = (const float4*)&swkT[j][0];
      const float4* wv4 = (const float4*)&swkT[32+j][0];
      float ka=0, va=0;
      #pragma unroll
      for (int i4=0;i4<8;i4++){
        float4 wk = wk4[i4], wv = wv4[i4];
        ka += xn[4*i4+0]*wk.x + xn[4*i4+1]*wk.y + xn[4*i4+2]*wk.z + xn[4*i4+3]*wk.w;
        va += xn[4*i4+0]*wv.x + xn[4*i4+1]*wv.y + xn[4*i4+2]*wv.z + xn[4*i4+3]*wv.w;
      }
      sk[tloc][j]=ka; sv[tloc][j]=va;
    }
  }
  __syncthreads();
  const int hh = tid>>6, f = tid&63;
  float pm0,pm1,pm2,pm3,pm4,pm5,pm6,pm7;
  {
    const float* pmp = proj_mat + ((size_t)(l*4+hh)*8)*64 + f;
    pm0=pmp[0]; pm1=pmp[64]; pm2=pmp[128]; pm3=pmp[192];
    pm4=pmp[256]; pm5=pmp[320]; pm6=pmp[384]; pm7=pmp[448];
  }
  float a0=0,a1=0,a2=0,a3=0,a4=0,a5=0,a6=0,a7=0;
  #pragma unroll 4
  for (int t=0;t<128;t++){
    const float4* k4 = (const float4*)&sk[t][hh*8];
    const float4* v4 = (const float4*)&sv[t][hh*8];
    float4 ka = k4[0], kb = k4[1];
    float kd = ka.x*pm0 + ka.y*pm1 + ka.z*pm2 + ka.w*pm3
             + kb.x*pm4 + kb.y*pm5 + kb.z*pm6 + kb.w*pm7;
    const float Kf = elu1_f(kd);
    float4 va = v4[0], vb = v4[1];
    a0 += Kf*va.x; a1 += Kf*va.y; a2 += Kf*va.z; a3 += Kf*va.w;
    a4 += Kf*vb.x; a5 += Kf*vb.y; a6 += Kf*vb.z; a7 += Kf*vb.w;
  }
  float4* dst = (float4*)(kvpart + (size_t)blockIdx.x*2048 + tid*8);
  dst[0] = make_float4(a0,a1,a2,a3);
  dst[1] = make_float4(a4,a5,a6,a7);
}

// fixed-order hierarchical KV reduction: 2000 partials -> 10 chunks -> final
__global__ __launch_bounds__(256) void k_kv_reduce1(
    const float* __restrict__ kvpart, float* __restrict__ p2)
{
  const int chunk = blockIdx.x >> 3;                 // 0..9
  const int e = (blockIdx.x&7)*256 + threadIdx.x;    // 0..2047
  float acc=0.0f;
  const int base = chunk*200;
  for (int ab=0; ab<200; ab++) acc += kvpart[(size_t)(base+ab)*2048 + e];
  p2[chunk*2048 + e] = acc;
}

__global__ __launch_bounds__(256) void k_kv_reduce2(
    const float* __restrict__ p2, float* __restrict__ KV)
{
  const int hf = threadIdx.x;
  float acc[8];
  #pragma unroll
  for (int d=0;d<8;d++) acc[d]=0.0f;
  for (int c=0;c<10;c++){
    #pragma unroll
    for (int d=0;d<8;d++) acc[d] += p2[c*2048 + hf*8 + d];
  }
  #pragma unroll
  for (int d=0;d<8;d++) KV[hf*8+d]=acc[d];
}

// ---------------------------------------------------------------------------
// Pass C1: ln1 -> q -> Qfeat -> attn (den = sum of ao) -> proj + residual.
// 8 lanes per token; slim LDS (~29 KB) + launch_bounds(256,4) => VGPR<=128.
// ---------------------------------------------------------------------------
__global__ __launch_bounds__(256,4) void k_attn(
    float* __restrict__ hbuf,
    const float* __restrict__ ln1_g, const float* __restrict__ ln1_b,
    const float* __restrict__ wqkv, const float* __restrict__ proj_mat,
    const float* __restrict__ wproj, const float* __restrict__ bproj,
    const float* __restrict__ KV, int l)
{
  __shared__ __align__(16) float swq[32][32];
  __shared__ __align__(16) float spmT[4][64][8];   // [h][f][d]
  __shared__ __align__(16) float sKVT[4][64][8];   // [h][f][d]
  __shared__ __align__(16) float swp[32][32];
  __shared__ float s1g[32],s1b[32],sbp[32];
  __shared__ __align__(16) float rowA[32][36];
  const int tid = threadIdx.x;
  for (int i=tid;i<1024;i+=256) swq[i>>5][i&31] = wqkv[l*3072 + (i>>5)*96 + (i&31)];
  for (int i=tid;i<2048;i+=256){
    int hh=i>>9, f=(i>>3)&63, d=i&7;
    spmT[hh][f][d] = proj_mat[l*2048 + hh*512 + d*64 + f];
  }
  for (int i=tid;i<2048;i+=256) (&sKVT[0][0][0])[i] = KV[i];
  for (int i=tid;i<1024;i+=256) (&swp[0][0])[i] = wproj[l*1024+i];
  if (tid<32){ s1g[tid]=ln1_g[l*32+tid]; s1b[tid]=ln1_b[l*32+tid];
               sbp[tid]=bproj[l*32+tid]; }
  __syncthreads();

  const int t  = tid >> 3;       // token slot (0..31)
  const int s  = tid & 7;        // sub-lane (0..7)
  const int c0 = s*4;
  const int tok = blockIdx.x*32 + t;
  float4* hp = (float4*)(hbuf + (size_t)tok*32);
  float4 hx = hp[s];
  float4* rA4 = (float4*)&rowA[t][0];

  // ---- ln1 ----
  float sum = hx.x+hx.y+hx.z+hx.w;
  sum += __shfl_xor(sum,1); sum += __shfl_xor(sum,2); sum += __shfl_xor(sum,4);
  float mu = sum*(1.0f/32.0f);
  float d0=hx.x-mu, d1=hx.y-mu, d2=hx.z-mu, d3=hx.w-mu;
  float vv = d0*d0+d1*d1+d2*d2+d3*d3;
  vv += __shfl_xor(vv,1); vv += __shfl_xor(vv,2); vv += __shfl_xor(vv,4);
  float inv = rsqrtf(vv*(1.0f/32.0f)+EPS);
  rA4[s] = make_float4(d0*inv*s1g[c0+0]+s1b[c0+0], d1*inv*s1g[c0+1]+s1b[c0+1],
                       d2*inv*s1g[c0+2]+s1b[c0+2], d3*inv*s1g[c0+3]+s1b[c0+3]);

  // ---- q (own 4 channels) ----
  {
    float q0=0,q1=0,q2=0,q3=0;
    #pragma unroll
    for (int i4=0;i4<8;i4++){
      float4 xv = rA4[i4];
      float4 w0 = *(const float4*)&swq[4*i4+0][c0];
      float4 w1r= *(const float4*)&swq[4*i4+1][c0];
      float4 w2r= *(const float4*)&swq[4*i4+2][c0];
      float4 w3 = *(const float4*)&swq[4*i4+3][c0];
      q0 += xv.x*w0.x + xv.y*w1r.x + xv.z*w2r.x + xv.w*w3.x;
      q1 += xv.x*w0.y + xv.y*w1r.y + xv.z*w2r.y + xv.w*w3.y;
      q2 += xv.x*w0.z + xv.y*w1r.z + xv.z*w2r.z + xv.w*w3.z;
      q3 += xv.x*w0.w + xv.y*w1r.w + xv.z*w2r.w + xv.w*w3.w;
    }
    rA4[s] = make_float4(q0,q1,q2,q3);
  }

  // ---- attention per head; den = sum of reduced ao ----
  #pragma unroll
  for (int hh=0;hh<4;hh++){
    float4 qa = rA4[hh*2], qb = rA4[hh*2+1];
    float a0=0,a1=0,a2=0,a3=0,a4=0,a5=0,a6=0,a7=0;
    #pragma unroll
    for (int k=0;k<8;k++){
      const int f = k*8 + s;
      const float4* pm4 = (const float4*)&spmT[hh][f][0];
      float4 pa = pm4[0], pb = pm4[1];
      float qd = qa.x*pa.x+qa.y*pa.y+qa.z*pa.z+qa.w*pa.w
               + qb.x*pb.x+qb.y*pb.y+qb.z*pb.z+qb.w*pb.w;
      const float Qf = elu1_f(qd);
      const float4* kv4 = (const float4*)&sKVT[hh][f][0];
      float4 va = kv4[0], vb = kv4[1];
      a0 += Qf*va.x; a1 += Qf*va.y; a2 += Qf*va.z; a3 += Qf*va.w;
      a4 += Qf*vb.x; a5 += Qf*vb.y; a6 += Qf*vb.z; a7 += Qf*vb.w;
    }
    a0 += __shfl_xor(a0,1); a0 += __shfl_xor(a0,2); a0 += __shfl_xor(a0,4);
    a1 += __shfl_xor(a1,1); a1 += __shfl_xor(a1,2); a1 += __shfl_xor(a1,4);
    a2 += __shfl_xor(a2,1); a2 += __shfl_xor(a2,2); a2 += __shfl_xor(a2,4);
    a3 += __shfl_xor(a3,1); a3 += __shfl_xor(a3,2); a3 += __shfl_xor(a3,4);
    a4 += __shfl_xor(a4,1); a4 += __shfl_xor(a4,2); a4 += __shfl_xor(a4,4);
    a5 += __shfl_xor(a5,1); a5 += __shfl_xor(a5,2); a5 += __shfl_xor(a5,4);
    a6 += __shfl_xor(a6,1); a6 += __shfl_xor(a6,2); a6 += __shfl_xor(a6,4);
    a7 += __shfl_xor(a7,1); a7 += __shfl_xor(a7,2); a7 += __shfl_xor(a7,4);
    const float den = a0+a1+a2+a3+a4+a5+a6+a7;   // == sum_f Qf * KVs
    const float z = 1.0f/den;
    if (s == hh*2)   rA4[hh*2]   = make_float4(a0*z,a1*z,a2*z,a3*z);
    if (s == hh*2+1) rA4[hh*2+1] = make_float4(a4*z,a5*z,a6*z,a7*z);
  }

  // ---- proj + residual ----
  {
    float p0=sbp[c0+0], p1=sbp[c0+1], p2=sbp[c0+2], p3=sbp[c0+3];
    #pragma unroll
    for (int i4=0;i4<8;i4++){
      float4 av = rA4[i4];
      float4 w0 = *(const float4*)&swp[4*i4+0][c0];
      float4 w1r= *(const float4*)&swp[4*i4+1][c0];
      float4 w2r= *(const float4*)&swp[4*i4+2][c0];
      float4 w3 = *(const float4*)&swp[4*i4+3][c0];
      p0 += av.x*w0.x + av.y*w1r.x + av.z*w2r.x + av.w*w3.x;
      p1 += av.x*w0.y + av.y*w1r.y + av.z*w2r.y + av.w*w3.y;
      p2 += av.x*w0.z + av.y*w1r.z + av.z*w2r.z + av.w*w3.z;
      p3 += av.x*w0.w + av.y*w1r.w + av.z*w2r.w + av.w*w3.w;
    }
    hp[s] = make_float4(hx.x+p0, hx.y+p1, hx.z+p2, hx.w+p3);
  }
}

// ---------------------------------------------------------------------------
// Pass C2: ln2 -> FFN(gelu) + residual. Slim LDS (~30 KB), VGPR<=128.
// ---------------------------------------------------------------------------
__global__ __launch_bounds__(256,4) void k_ffn(
    float* __restrict__ hbuf,
    const float* __restrict__ ln2_g, const float* __restrict__ ln2_b,
    const float* __restrict__ w1, const float* __restrict__ b1,
    const float* __restrict__ w2, const float* __restrict__ b2, int l)
{
  __shared__ __align__(16) float sw1[32][64];
  __shared__ __align__(16) float sw2[64][32];
  __shared__ float s2g[32],s2b[32],sb1[64],sb2[32];
  __shared__ __align__(16) float rowM[32][36];
  __shared__ __align__(16) float rowG[32][68];
  const int tid = threadIdx.x;
  for (int i=tid;i<2048;i+=256) (&sw1[0][0])[i] = w1[l*2048+i];
  for (int i=tid;i<2048;i+=256) (&sw2[0][0])[i] = w2[l*2048+i];
  if (tid<32){ s2g[tid]=ln2_g[l*32+tid]; s2b[tid]=ln2_b[l*32+tid];
               sb2[tid]=b2[l*32+tid]; }
  if (tid<64) sb1[tid]=b1[l*64+tid];
  __syncthreads();

  const int t  = tid >> 3;
  const int s  = tid & 7;
  const int c0 = s*4;
  const int tok = blockIdx.x*32 + t;
  float4* hp = (float4*)(hbuf + (size_t)tok*32);
  float4 hx = hp[s];
  float4* rM4 = (float4*)&rowM[t][0];
  float4* rG4 = (float4*)&rowG[t][0];

  // ---- ln2 ----
  float sum = hx.x+hx.y+hx.z+hx.w;
  sum += __shfl_xor(sum,1); sum += __shfl_xor(sum,2); sum += __shfl_xor(sum,4);
  float mu = sum*(1.0f/32.0f);
  float d0=hx.x-mu, d1=hx.y-mu, d2=hx.z-mu, d3=hx.w-mu;
  float vv = d0*d0+d1*d1+d2*d2+d3*d3;
  vv += __shfl_xor(vv,1); vv += __shfl_xor(vv,2); vv += __shfl_xor(vv,4);
  float inv = rsqrtf(vv*(1.0f/32.0f)+EPS);
  rM4[s] = make_float4(d0*inv*s2g[c0+0]+s2b[c0+0], d1*inv*s2g[c0+1]+s2b[c0+1],
                       d2*inv*s2g[c0+2]+s2b[c0+2], d3*inv*s2g[c0+3]+s2b[c0+3]);

  // ---- FFN1: lane computes g_j, j = s*8..s*8+7 ----
  {
    float g[8];
    #pragma unroll
    for (int k=0;k<8;k++) g[k]=sb1[s*8+k];
    #pragma unroll
    for (int i4=0;i4<8;i4++){
      float4 mv = rM4[i4];
      const float mm[4] = {mv.x, mv.y, mv.z, mv.w};
      #pragma unroll
      for (int ii=0;ii<4;ii++){
        const float4* w14 = (const float4*)&sw1[4*i4+ii][s*8];
        float4 wa = w14[0], wb = w14[1];
        g[0] += mm[ii]*wa.x; g[1] += mm[ii]*wa.y; g[2] += mm[ii]*wa.z; g[3] += mm[ii]*wa.w;
        g[4] += mm[ii]*wb.x; g[5] += mm[ii]*wb.y; g[6] += mm[ii]*wb.z; g[7] += mm[ii]*wb.w;
      }
    }
    rG4[s*2+0] = make_float4(gelu_f(g[0]),gelu_f(g[1]),gelu_f(g[2]),gelu_f(g[3]));
    rG4[s*2+1] = make_float4(gelu_f(g[4]),gelu_f(g[5]),gelu_f(g[6]),gelu_f(g[7]));
  }

  // ---- FFN2 + residual ----
  {
    float f0=sb2[c0+0], f1=sb2[c0+1], f2=sb2[c0+2], f3=sb2[c0+3];
    #pragma unroll
    for (int j4=0;j4<16;j4++){
      float4 gv = rG4[j4];
      const float gg[4] = {gv.x, gv.y, gv.z, gv.w};
      #pragma unroll
      for (int jj=0;jj<4;jj++){
        float4 w = *(const float4*)&sw2[4*j4+jj][c0];
        f0 += gg[jj]*w.x; f1 += gg[jj]*w.y; f2 += gg[jj]*w.z; f3 += gg[jj]*w.w;
      }
    }
    hp[s] = make_float4(hx.x+f0, hx.y+f1, hx.z+f2, hx.w+f3);
  }
}

// ---------------------------------------------------------------------------
// Final: layernorm -> pool score s; softmax over N per batch; weighted sum; fc
// ---------------------------------------------------------------------------
__global__ __launch_bounds__(256) void k_pool_score(
    const float* __restrict__ hbuf, const float* __restrict__ ng,
    const float* __restrict__ nb, const float* __restrict__ pw,
    const float* __restrict__ pb, float* __restrict__ s)
{
  const int tok = blockIdx.x*256 + threadIdx.x;
  float hx[32];
  const float4* src = (const float4*)(hbuf + (size_t)tok*32);
  #pragma unroll
  for (int i=0;i<8;i++){ float4 v4=src[i]; hx[4*i]=v4.x; hx[4*i+1]=v4.y; hx[4*i+2]=v4.z; hx[4*i+3]=v4.w; }
  float mu=0;
  #pragma unroll
  for (int i=0;i<32;i++) mu += hx[i];
  mu *= (1.0f/32.0f);
  float vs=0;
  #pragma unroll
  for (int i=0;i<32;i++){ float d=hx[i]-mu; vs += d*d; }
  const float inv = rsqrtf(vs*(1.0f/32.0f)+EPS);
  float sv = pb[0];
  #pragma unroll
  for (int i=0;i<32;i++) sv += ((hx[i]-mu)*inv*ng[i]+nb[i])*pw[i];
  s[tok]=sv;
}

__global__ __launch_bounds__(256) void k_softmax_stats(
    const float* __restrict__ s, float* __restrict__ bmax, float* __restrict__ bsum)
{
  __shared__ float red[256];
  __shared__ float smax_sh;
  const int b = blockIdx.x, tid = threadIdx.x;
  const float* sbp = s + (size_t)b*TOKB;
  float mx = -INFINITY;
  for (int i=tid;i<TOKB;i+=256) mx = fmaxf(mx, sbp[i]);
  red[tid]=mx; __syncthreads();
  for (int st=128;st>0;st>>=1){ if(tid<st) red[tid]=fmaxf(red[tid],red[tid+st]); __syncthreads(); }
  if (tid==0) smax_sh = red[0];
  __syncthreads();
  const float smax = smax_sh;
  float acc=0.0f;
  for (int i=tid;i<TOKB;i+=256) acc += __expf(sbp[i]-smax);
  __syncthreads();
  red[tid]=acc; __syncthreads();
  for (int st=128;st>0;st>>=1){ if(tid<st) red[tid]+=red[tid+st]; __syncthreads(); }
  if (tid==0){ bmax[b]=smax; bsum[b]=red[0]; }
}

__global__ __launch_bounds__(256) void k_pool_partial(
    const float* __restrict__ hbuf, const float* __restrict__ ng,
    const float* __restrict__ nb, const float* __restrict__ s,
    const float* __restrict__ bmax, float* __restrict__ pp)
{
  __shared__ float red[256][33];
  const int b = blockIdx.x/63, ch = blockIdx.x%63;
  const int tid = threadIdx.x;
  const int n = ch*256+tid;
  if (n < TOKB) {
    const int tok = b*TOKB+n;
    float hx[32];
    const float4* src = (const float4*)(hbuf + (size_t)tok*32);
    #pragma unroll
    for (int i=0;i<8;i++){ float4 v4=src[i]; hx[4*i]=v4.x; hx[4*i+1]=v4.y; hx[4*i+2]=v4.z; hx[4*i+3]=v4.w; }
    float mu=0;
    #pragma unroll
    for (int i=0;i<32;i++) mu += hx[i];
    mu *= (1.0f/32.0f);
    float vs=0;
    #pragma unroll
    for (int i=0;i<32;i++){ float d=hx[i]-mu; vs += d*d; }
    const float inv = rsqrtf(vs*(1.0f/32.0f)+EPS);
    const float w = __expf(s[tok]-bmax[b]);
    #pragma unroll
    for (int i=0;i<32;i++) red[tid][i] = w*((hx[i]-mu)*inv*ng[i]+nb[i]);
  } else {
    #pragma unroll
    for (int i=0;i<32;i++) red[tid][i]=0.0f;
  }
  __syncthreads();
  if (tid<32){
    float acc=0.0f;
    for (int t=0;t<256;t++) acc += red[t][tid];
    pp[(size_t)blockIdx.x*32 + tid] = acc;
  }
}

__global__ __launch_bounds__(64) void k_pool_final(
    const float* __restrict__ pp, const float* __restrict__ bsum,
    const float* __restrict__ fcw, const float* __restrict__ fcb,
    float* __restrict__ out)
{
  __shared__ float sp[32];
  const int b = blockIdx.x, tid = threadIdx.x;
  if (tid<32){
    float acc=0.0f;
    for (int ch=0;ch<63;ch++) acc += pp[(size_t)(b*63+ch)*32+tid];
    sp[tid] = acc / bsum[b];
  }
  __syncthreads();
  if (tid<2){
    float v = fcb[tid];
    for (int o=0;o<32;o++) v += sp[o]*fcw[o*2+tid];
    out[b*2+tid]=v;
  }
}

extern "C" void kernel_launch(void* const* d_in, const int* in_sizes, int n_in,
                              void* d_out, int out_size, void* d_ws, size_t ws_size,
                              hipStream_t stream)
{
  const float* x      = (const float*)d_in[0];
  const float* band_w = (const float*)d_in[1];
  const float* pw_w   = (const float*)d_in[2];
  const float* bn_g   = (const float*)d_in[3];
  const float* bn_b   = (const float*)d_in[4];
  const float* bn_m   = (const float*)d_in[5];
  const float* bn_v   = (const float*)d_in[6];
  const float* ln1_g  = (const float*)d_in[7];
  const float* ln1_b  = (const float*)d_in[8];
  const float* wqkv   = (const float*)d_in[9];
  const float* proj   = (const float*)d_in[10];
  const float* wproj  = (const float*)d_in[11];
  const float* bprojp = (const float*)d_in[12];
  const float* ln2_g  = (const float*)d_in[13];
  const float* ln2_b  = (const float*)d_in[14];
  const float* w1     = (const float*)d_in[15];
  const float* b1     = (const float*)d_in[16];
  const float* w2     = (const float*)d_in[17];
  const float* b2     = (const float*)d_in[18];
  const float* norm_g = (const float*)d_in[19];
  const float* norm_b = (const float*)d_in[20];
  const float* pool_w = (const float*)d_in[21];
  const float* pool_b = (const float*)d_in[22];
  const float* fc_w   = (const float*)d_in[23];
  const float* fc_b   = (const float*)d_in[24];
  float* out = (float*)d_out;
  float* ws  = (float*)d_ws;

  float* hbuf  = ws;                       // 8,192,000 floats (32 MB)
  float* kvp   = hbuf + 8192000;           // 2000*2048 = 4,096,000
  float* p2    = kvp  + 4096000;           // 10*2048 = 20,480
  float* KV    = p2   + 20480;             // 2048
  float* sbuf  = KV   + 2048;              // 256,000
  float* bmax  = sbuf + 256000;            // 16
  float* bsum  = bmax + 16;                // 16
  float* pp    = bsum + 16;                // 16*63*32 = 32,256

  k_tokenize<<<1024,256,0,stream>>>(x, band_w, pw_w, bn_g, bn_b, bn_m, bn_v, hbuf);
  for (int l=0;l<2;l++){
    k_kv_partial<<<2000,256,0,stream>>>(hbuf, ln1_g, ln1_b, wqkv, proj, kvp, l);
    k_kv_reduce1<<<80,256,0,stream>>>(kvp, p2);
    k_kv_reduce2<<<1,256,0,stream>>>(p2, KV);
    k_attn<<<8000,256,0,stream>>>(hbuf, ln1_g, ln1_b, wqkv, proj, wproj, bprojp, KV, l);
    k_ffn<<<8000,256,0,stream>>>(hbuf, ln2_g, ln2_b, w1, b1, w2, b2, l);
  }
  k_pool_score<<<1000,256,0,stream>>>(hbuf, norm_g, norm_b, pool_w, pool_b, sbuf);
  k_softmax_stats<<<16,256,0,stream>>>(sbuf, bmax, bsum);
  k_pool_partial<<<16*63,256,0,stream>>>(hbuf, norm_g, norm_b, sbuf, bmax, pp);
  k_pool_final<<<16,64,0,stream>>>(pp, bsum, fc_w, fc_b, out);
}

// Round 6
// 811.931 us; speedup vs baseline: 2.3344x; 2.3344x over previous
//
#include <hip/hip_runtime.h>
#include <math.h>

#define NTOK   256000
#define TOKB   16000
#define EPS    1e-5f

__device__ __forceinline__ float gelu_f(float x){
  return 0.5f*x*(1.0f+erff(x*0.70710678118654752440f));
}
__device__ __forceinline__ float elu1_f(float x){
  return x>0.0f ? x+1.0f : __expf(x);   // elu(x)+1
}

// ---------------------------------------------------------------------------
// Tokenizer: band conv(51) -> 1x1 conv(4->32) -> BN -> GELU -> avgpool(4)
// ---------------------------------------------------------------------------
__global__ __launch_bounds__(256) void k_tokenize(
    const float* __restrict__ x, const float* __restrict__ band_w,
    const float* __restrict__ pw_w, const float* __restrict__ bn_g,
    const float* __restrict__ bn_b, const float* __restrict__ bn_m,
    const float* __restrict__ bn_v, float* __restrict__ hout)
{
  __shared__ float sx[1050];
  __shared__ float sbw[4][51];
  __shared__ float spw[32][4];
  __shared__ float sscale[32], sshift[32];
  const int tid = threadIdx.x;
  const int b = blockIdx.x >> 6, e = blockIdx.x & 63;
  const float* xr = x + (size_t)(b*64 + e)*1000;
  for (int i=tid;i<1050;i+=256){ int t=i-25; sx[i]=(t>=0&&t<1000)?xr[t]:0.0f; }
  for (int i=tid;i<204;i+=256){ sbw[i/51][i%51] = band_w[i]; }
  for (int i=tid;i<128;i+=256){ spw[i>>2][i&3] = pw_w[i]; }
  if (tid<32){ float sc = bn_g[tid]*rsqrtf(bn_v[tid]+EPS);
               sscale[tid]=sc; sshift[tid]=bn_b[tid]-bn_m[tid]*sc; }
  __syncthreads();
  const int tp = tid;
  if (tp < 250) {
    float acc[32];
    #pragma unroll
    for (int o=0;o<32;o++) acc[o]=0.0f;
    for (int j=0;j<4;j++){
      const int t = 4*tp+j;
      float c0=0,c1=0,c2=0,c3=0;
      for (int k=0;k<51;k++){
        float xv = sx[t+k];
        c0 += xv*sbw[0][k]; c1 += xv*sbw[1][k];
        c2 += xv*sbw[2][k]; c3 += xv*sbw[3][k];
      }
      #pragma unroll
      for (int o=0;o<32;o++){
        float hv = spw[o][0]*c0 + spw[o][1]*c1 + spw[o][2]*c2 + spw[o][3]*c3;
        hv = hv*sscale[o] + sshift[o];
        acc[o] += gelu_f(hv);
      }
    }
    const int tok = b*TOKB + e*250 + tp;
    float4* dst = (float4*)(hout + (size_t)tok*32);
    #pragma unroll
    for (int o8=0;o8<8;o8++)
      dst[o8] = make_float4(acc[o8*4]*0.25f, acc[o8*4+1]*0.25f,
                            acc[o8*4+2]*0.25f, acc[o8*4+3]*0.25f);
  }
}

// ---------------------------------------------------------------------------
// Pass A: per 128-token tile: ln1 -> k,v -> K-features -> partial KV[h,f,d]
// ---------------------------------------------------------------------------
__global__ __launch_bounds__(256) void k_kv_partial(
    const float* __restrict__ hbuf, const float* __restrict__ ln1_g,
    const float* __restrict__ ln1_b, const float* __restrict__ wqkv,
    const float* __restrict__ proj_mat, float* __restrict__ kvpart, int l)
{
  __shared__ __align__(16) float sk[128][36];
  __shared__ __align__(16) float sv[128][36];
  __shared__ __align__(16) float swkT[64][32];   // [j][i]: j=0..31 k-cols, 32..63 v-cols
  __shared__ float sg[32], sb[32];
  const int tid = threadIdx.x;
  const float* W = wqkv + l*32*96;
  for (int idx=tid;idx<2048;idx+=256){
    int i = idx&31, j = idx>>5;
    swkT[j][i] = W[i*96 + 32 + j];
  }
  if (tid<32){ sg[tid]=ln1_g[l*32+tid]; sb[tid]=ln1_b[l*32+tid]; }
  __syncthreads();
  {
    const int tloc = tid>>1, half = tid&1;
    const int tok = blockIdx.x*128 + tloc;
    float hx[32];
    const float4* src = (const float4*)(hbuf + (size_t)tok*32);
    #pragma unroll
    for (int i=0;i<8;i++){ float4 v4=src[i]; hx[4*i]=v4.x; hx[4*i+1]=v4.y; hx[4*i+2]=v4.z; hx[4*i+3]=v4.w; }
    float mu=0;
    #pragma unroll
    for (int i=0;i<32;i++) mu += hx[i];
    mu *= (1.0f/32.0f);
    float vs=0;
    #pragma unroll
    for (int i=0;i<32;i++){ float d=hx[i]-mu; vs += d*d; }
    const float inv = rsqrtf(vs*(1.0f/32.0f)+EPS);
    float xn[32];
    #pragma unroll
    for (int i=0;i<32;i++) xn[i] = (hx[i]-mu)*inv*sg[i]+sb[i];
    const int j0 = half*16;
    #pragma unroll 4
    for (int jj=0;jj<16;jj++){
      const int j = j0+jj;
      const float4* wk4 = (const float4*)&swkT[j][0];
      const float4* wv4 = (const float4*)&swkT[32+j][0];
      float ka=0, va=0;
      #pragma unroll
      for (int i4=0;i4<8;i4++){
        float4 wk = wk4[i4], wv = wv4[i4];
        ka += xn[4*i4+0]*wk.x + xn[4*i4+1]*wk.y + xn[4*i4+2]*wk.z + xn[4*i4+3]*wk.w;
        va += xn[4*i4+0]*wv.x + xn[4*i4+1]*wv.y + xn[4*i4+2]*wv.z + xn[4*i4+3]*wv.w;
      }
      sk[tloc][j]=ka; sv[tloc][j]=va;
    }
  }
  __syncthreads();
  const int hh = tid>>6, f = tid&63;
  float pm0,pm1,pm2,pm3,pm4,pm5,pm6,pm7;
  {
    const float* pmp = proj_mat + ((size_t)(l*4+hh)*8)*64 + f;
    pm0=pmp[0]; pm1=pmp[64]; pm2=pmp[128]; pm3=pmp[192];
    pm4=pmp[256]; pm5=pmp[320]; pm6=pmp[384]; pm7=pmp[448];
  }
  float a0=0,a1=0,a2=0,a3=0,a4=0,a5=0,a6=0,a7=0;
  #pragma unroll 4
  for (int t=0;t<128;t++){
    const float4* k4 = (const float4*)&sk[t][hh*8];
    const float4* v4 = (const float4*)&sv[t][hh*8];
    float4 ka = k4[0], kb = k4[1];
    float kd = ka.x*pm0 + ka.y*pm1 + ka.z*pm2 + ka.w*pm3
             + kb.x*pm4 + kb.y*pm5 + kb.z*pm6 + kb.w*pm7;
    const float Kf = elu1_f(kd);
    float4 va = v4[0], vb = v4[1];
    a0 += Kf*va.x; a1 += Kf*va.y; a2 += Kf*va.z; a3 += Kf*va.w;
    a4 += Kf*vb.x; a5 += Kf*vb.y; a6 += Kf*vb.z; a7 += Kf*vb.w;
  }
  float4* dst = (float4*)(kvpart + (size_t)blockIdx.x*2048 + tid*8);
  dst[0] = make_float4(a0,a1,a2,a3);
  dst[1] = make_float4(a4,a5,a6,a7);
}

// fixed-order hierarchical KV reduction: 2000 partials -> 10 chunks -> final
__global__ __launch_bounds__(256) void k_kv_reduce1(
    const float* __restrict__ kvpart, float* __restrict__ p2)
{
  const int chunk = blockIdx.x >> 3;                 // 0..9
  const int e = (blockIdx.x&7)*256 + threadIdx.x;    // 0..2047
  float acc=0.0f;
  const int base = chunk*200;
  for (int ab=0; ab<200; ab++) acc += kvpart[(size_t)(base+ab)*2048 + e];
  p2[chunk*2048 + e] = acc;
}

__global__ __launch_bounds__(256) void k_kv_reduce2(
    const float* __restrict__ p2, float* __restrict__ KV)
{
  const int hf = threadIdx.x;
  float acc[8];
  #pragma unroll
  for (int d=0;d<8;d++) acc[d]=0.0f;
  for (int c=0;c<10;c++){
    #pragma unroll
    for (int d=0;d<8;d++) acc[d] += p2[c*2048 + hf*8 + d];
  }
  #pragma unroll
  for (int d=0;d<8;d++) KV[hf*8+d]=acc[d];
}

// ---------------------------------------------------------------------------
// Pass C1: ln1 -> q -> Qfeat -> attn (den = sum of ao) -> proj + residual.
// 8 lanes per token; slim LDS (~29 KB). No min-waves clause (R5 lesson:
// forcing 4 waves/EU drove VGPR to 64 and spilled ~3 GB to scratch).
// ---------------------------------------------------------------------------
__global__ __launch_bounds__(256) void k_attn(
    float* __restrict__ hbuf,
    const float* __restrict__ ln1_g, const float* __restrict__ ln1_b,
    const float* __restrict__ wqkv, const float* __restrict__ proj_mat,
    const float* __restrict__ wproj, const float* __restrict__ bproj,
    const float* __restrict__ KV, int l)
{
  __shared__ __align__(16) float swq[32][32];
  __shared__ __align__(16) float spmT[4][64][8];   // [h][f][d]
  __shared__ __align__(16) float sKVT[4][64][8];   // [h][f][d]
  __shared__ __align__(16) float swp[32][32];
  __shared__ float s1g[32],s1b[32],sbp[32];
  __shared__ __align__(16) float rowA[32][36];
  const int tid = threadIdx.x;
  for (int i=tid;i<1024;i+=256) swq[i>>5][i&31] = wqkv[l*3072 + (i>>5)*96 + (i&31)];
  for (int i=tid;i<2048;i+=256){
    int hh=i>>9, f=(i>>3)&63, d=i&7;
    spmT[hh][f][d] = proj_mat[l*2048 + hh*512 + d*64 + f];
  }
  for (int i=tid;i<2048;i+=256) (&sKVT[0][0][0])[i] = KV[i];
  for (int i=tid;i<1024;i+=256) (&swp[0][0])[i] = wproj[l*1024+i];
  if (tid<32){ s1g[tid]=ln1_g[l*32+tid]; s1b[tid]=ln1_b[l*32+tid];
               sbp[tid]=bproj[l*32+tid]; }
  __syncthreads();

  const int t  = tid >> 3;       // token slot (0..31)
  const int s  = tid & 7;        // sub-lane (0..7)
  const int c0 = s*4;
  const int tok = blockIdx.x*32 + t;
  float4* hp = (float4*)(hbuf + (size_t)tok*32);
  float4 hx = hp[s];
  float4* rA4 = (float4*)&rowA[t][0];

  // ---- ln1 ----
  float sum = hx.x+hx.y+hx.z+hx.w;
  sum += __shfl_xor(sum,1); sum += __shfl_xor(sum,2); sum += __shfl_xor(sum,4);
  float mu = sum*(1.0f/32.0f);
  float d0=hx.x-mu, d1=hx.y-mu, d2=hx.z-mu, d3=hx.w-mu;
  float vv = d0*d0+d1*d1+d2*d2+d3*d3;
  vv += __shfl_xor(vv,1); vv += __shfl_xor(vv,2); vv += __shfl_xor(vv,4);
  float inv = rsqrtf(vv*(1.0f/32.0f)+EPS);
  rA4[s] = make_float4(d0*inv*s1g[c0+0]+s1b[c0+0], d1*inv*s1g[c0+1]+s1b[c0+1],
                       d2*inv*s1g[c0+2]+s1b[c0+2], d3*inv*s1g[c0+3]+s1b[c0+3]);

  // ---- q (own 4 channels) ----
  {
    float q0=0,q1=0,q2=0,q3=0;
    #pragma unroll
    for (int i4=0;i4<8;i4++){
      float4 xv = rA4[i4];
      float4 w0 = *(const float4*)&swq[4*i4+0][c0];
      float4 w1r= *(const float4*)&swq[4*i4+1][c0];
      float4 w2r= *(const float4*)&swq[4*i4+2][c0];
      float4 w3 = *(const float4*)&swq[4*i4+3][c0];
      q0 += xv.x*w0.x + xv.y*w1r.x + xv.z*w2r.x + xv.w*w3.x;
      q1 += xv.x*w0.y + xv.y*w1r.y + xv.z*w2r.y + xv.w*w3.y;
      q2 += xv.x*w0.z + xv.y*w1r.z + xv.z*w2r.z + xv.w*w3.z;
      q3 += xv.x*w0.w + xv.y*w1r.w + xv.z*w2r.w + xv.w*w3.w;
    }
    rA4[s] = make_float4(q0,q1,q2,q3);
  }

  // ---- attention per head; den = sum of reduced ao ----
  #pragma unroll
  for (int hh=0;hh<4;hh++){
    float4 qa = rA4[hh*2], qb = rA4[hh*2+1];
    float a0=0,a1=0,a2=0,a3=0,a4=0,a5=0,a6=0,a7=0;
    #pragma unroll
    for (int k=0;k<8;k++){
      const int f = k*8 + s;
      const float4* pm4 = (const float4*)&spmT[hh][f][0];
      float4 pa = pm4[0], pb = pm4[1];
      float qd = qa.x*pa.x+qa.y*pa.y+qa.z*pa.z+qa.w*pa.w
               + qb.x*pb.x+qb.y*pb.y+qb.z*pb.z+qb.w*pb.w;
      const float Qf = elu1_f(qd);
      const float4* kv4 = (const float4*)&sKVT[hh][f][0];
      float4 va = kv4[0], vb = kv4[1];
      a0 += Qf*va.x; a1 += Qf*va.y; a2 += Qf*va.z; a3 += Qf*va.w;
      a4 += Qf*vb.x; a5 += Qf*vb.y; a6 += Qf*vb.z; a7 += Qf*vb.w;
    }
    a0 += __shfl_xor(a0,1); a0 += __shfl_xor(a0,2); a0 += __shfl_xor(a0,4);
    a1 += __shfl_xor(a1,1); a1 += __shfl_xor(a1,2); a1 += __shfl_xor(a1,4);
    a2 += __shfl_xor(a2,1); a2 += __shfl_xor(a2,2); a2 += __shfl_xor(a2,4);
    a3 += __shfl_xor(a3,1); a3 += __shfl_xor(a3,2); a3 += __shfl_xor(a3,4);
    a4 += __shfl_xor(a4,1); a4 += __shfl_xor(a4,2); a4 += __shfl_xor(a4,4);
    a5 += __shfl_xor(a5,1); a5 += __shfl_xor(a5,2); a5 += __shfl_xor(a5,4);
    a6 += __shfl_xor(a6,1); a6 += __shfl_xor(a6,2); a6 += __shfl_xor(a6,4);
    a7 += __shfl_xor(a7,1); a7 += __shfl_xor(a7,2); a7 += __shfl_xor(a7,4);
    const float den = a0+a1+a2+a3+a4+a5+a6+a7;   // == sum_f Qf * KVs
    const float z = 1.0f/den;
    if (s == hh*2)   rA4[hh*2]   = make_float4(a0*z,a1*z,a2*z,a3*z);
    if (s == hh*2+1) rA4[hh*2+1] = make_float4(a4*z,a5*z,a6*z,a7*z);
  }

  // ---- proj + residual ----
  {
    float p0=sbp[c0+0], p1=sbp[c0+1], p2=sbp[c0+2], p3=sbp[c0+3];
    #pragma unroll
    for (int i4=0;i4<8;i4++){
      float4 av = rA4[i4];
      float4 w0 = *(const float4*)&swp[4*i4+0][c0];
      float4 w1r= *(const float4*)&swp[4*i4+1][c0];
      float4 w2r= *(const float4*)&swp[4*i4+2][c0];
      float4 w3 = *(const float4*)&swp[4*i4+3][c0];
      p0 += av.x*w0.x + av.y*w1r.x + av.z*w2r.x + av.w*w3.x;
      p1 += av.x*w0.y + av.y*w1r.y + av.z*w2r.y + av.w*w3.y;
      p2 += av.x*w0.z + av.y*w1r.z + av.z*w2r.z + av.w*w3.z;
      p3 += av.x*w0.w + av.y*w1r.w + av.z*w2r.w + av.w*w3.w;
    }
    hp[s] = make_float4(hx.x+p0, hx.y+p1, hx.z+p2, hx.w+p3);
  }
}

// ---------------------------------------------------------------------------
// Pass C2: ln2 -> FFN(gelu) + residual. Slim LDS (~30 KB).
// ---------------------------------------------------------------------------
__global__ __launch_bounds__(256) void k_ffn(
    float* __restrict__ hbuf,
    const float* __restrict__ ln2_g, const float* __restrict__ ln2_b,
    const float* __restrict__ w1, const float* __restrict__ b1,
    const float* __restrict__ w2, const float* __restrict__ b2, int l)
{
  __shared__ __align__(16) float sw1[32][64];
  __shared__ __align__(16) float sw2[64][32];
  __shared__ float s2g[32],s2b[32],sb1[64],sb2[32];
  __shared__ __align__(16) float rowM[32][36];
  __shared__ __align__(16) float rowG[32][68];
  const int tid = threadIdx.x;
  for (int i=tid;i<2048;i+=256) (&sw1[0][0])[i] = w1[l*2048+i];
  for (int i=tid;i<2048;i+=256) (&sw2[0][0])[i] = w2[l*2048+i];
  if (tid<32){ s2g[tid]=ln2_g[l*32+tid]; s2b[tid]=ln2_b[l*32+tid];
               sb2[tid]=b2[l*32+tid]; }
  if (tid<64) sb1[tid]=b1[l*64+tid];
  __syncthreads();

  const int t  = tid >> 3;
  const int s  = tid & 7;
  const int c0 = s*4;
  const int tok = blockIdx.x*32 + t;
  float4* hp = (float4*)(hbuf + (size_t)tok*32);
  float4 hx = hp[s];
  float4* rM4 = (float4*)&rowM[t][0];
  float4* rG4 = (float4*)&rowG[t][0];

  // ---- ln2 ----
  float sum = hx.x+hx.y+hx.z+hx.w;
  sum += __shfl_xor(sum,1); sum += __shfl_xor(sum,2); sum += __shfl_xor(sum,4);
  float mu = sum*(1.0f/32.0f);
  float d0=hx.x-mu, d1=hx.y-mu, d2=hx.z-mu, d3=hx.w-mu;
  float vv = d0*d0+d1*d1+d2*d2+d3*d3;
  vv += __shfl_xor(vv,1); vv += __shfl_xor(vv,2); vv += __shfl_xor(vv,4);
  float inv = rsqrtf(vv*(1.0f/32.0f)+EPS);
  rM4[s] = make_float4(d0*inv*s2g[c0+0]+s2b[c0+0], d1*inv*s2g[c0+1]+s2b[c0+1],
                       d2*inv*s2g[c0+2]+s2b[c0+2], d3*inv*s2g[c0+3]+s2b[c0+3]);

  // ---- FFN1: lane computes g_j, j = s*8..s*8+7 ----
  {
    float g[8];
    #pragma unroll
    for (int k=0;k<8;k++) g[k]=sb1[s*8+k];
    #pragma unroll
    for (int i4=0;i4<8;i4++){
      float4 mv = rM4[i4];
      const float mm[4] = {mv.x, mv.y, mv.z, mv.w};
      #pragma unroll
      for (int ii=0;ii<4;ii++){
        const float4* w14 = (const float4*)&sw1[4*i4+ii][s*8];
        float4 wa = w14[0], wb = w14[1];
        g[0] += mm[ii]*wa.x; g[1] += mm[ii]*wa.y; g[2] += mm[ii]*wa.z; g[3] += mm[ii]*wa.w;
        g[4] += mm[ii]*wb.x; g[5] += mm[ii]*wb.y; g[6] += mm[ii]*wb.z; g[7] += mm[ii]*wb.w;
      }
    }
    rG4[s*2+0] = make_float4(gelu_f(g[0]),gelu_f(g[1]),gelu_f(g[2]),gelu_f(g[3]));
    rG4[s*2+1] = make_float4(gelu_f(g[4]),gelu_f(g[5]),gelu_f(g[6]),gelu_f(g[7]));
  }

  // ---- FFN2 + residual ----
  {
    float f0=sb2[c0+0], f1=sb2[c0+1], f2=sb2[c0+2], f3=sb2[c0+3];
    #pragma unroll
    for (int j4=0;j4<16;j4++){
      float4 gv = rG4[j4];
      const float gg[4] = {gv.x, gv.y, gv.z, gv.w};
      #pragma unroll
      for (int jj=0;jj<4;jj++){
        float4 w = *(const float4*)&sw2[4*j4+jj][c0];
        f0 += gg[jj]*w.x; f1 += gg[jj]*w.y; f2 += gg[jj]*w.z; f3 += gg[jj]*w.w;
      }
    }
    hp[s] = make_float4(hx.x+f0, hx.y+f1, hx.z+f2, hx.w+f3);
  }
}

// ---------------------------------------------------------------------------
// Final: layernorm -> pool score s; softmax over N per batch; weighted sum; fc
// ---------------------------------------------------------------------------
__global__ __launch_bounds__(256) void k_pool_score(
    const float* __restrict__ hbuf, const float* __restrict__ ng,
    const float* __restrict__ nb, const float* __restrict__ pw,
    const float* __restrict__ pb, float* __restrict__ s)
{
  const int tok = blockIdx.x*256 + threadIdx.x;
  float hx[32];
  const float4* src = (const float4*)(hbuf + (size_t)tok*32);
  #pragma unroll
  for (int i=0;i<8;i++){ float4 v4=src[i]; hx[4*i]=v4.x; hx[4*i+1]=v4.y; hx[4*i+2]=v4.z; hx[4*i+3]=v4.w; }
  float mu=0;
  #pragma unroll
  for (int i=0;i<32;i++) mu += hx[i];
  mu *= (1.0f/32.0f);
  float vs=0;
  #pragma unroll
  for (int i=0;i<32;i++){ float d=hx[i]-mu; vs += d*d; }
  const float inv = rsqrtf(vs*(1.0f/32.0f)+EPS);
  float sv = pb[0];
  #pragma unroll
  for (int i=0;i<32;i++) sv += ((hx[i]-mu)*inv*ng[i]+nb[i])*pw[i];
  s[tok]=sv;
}

__global__ __launch_bounds__(256) void k_softmax_stats(
    const float* __restrict__ s, float* __restrict__ bmax, float* __restrict__ bsum)
{
  __shared__ float red[256];
  __shared__ float smax_sh;
  const int b = blockIdx.x, tid = threadIdx.x;
  const float* sbp = s + (size_t)b*TOKB;
  float mx = -INFINITY;
  for (int i=tid;i<TOKB;i+=256) mx = fmaxf(mx, sbp[i]);
  red[tid]=mx; __syncthreads();
  for (int st=128;st>0;st>>=1){ if(tid<st) red[tid]=fmaxf(red[tid],red[tid+st]); __syncthreads(); }
  if (tid==0) smax_sh = red[0];
  __syncthreads();
  const float smax = smax_sh;
  float acc=0.0f;
  for (int i=tid;i<TOKB;i+=256) acc += __expf(sbp[i]-smax);
  __syncthreads();
  red[tid]=acc; __syncthreads();
  for (int st=128;st>0;st>>=1){ if(tid<st) red[tid]+=red[tid+st]; __syncthreads(); }
  if (tid==0){ bmax[b]=smax; bsum[b]=red[0]; }
}

__global__ __launch_bounds__(256) void k_pool_partial(
    const float* __restrict__ hbuf, const float* __restrict__ ng,
    const float* __restrict__ nb, const float* __restrict__ s,
    const float* __restrict__ bmax, float* __restrict__ pp)
{
  __shared__ float red[256][33];
  const int b = blockIdx.x/63, ch = blockIdx.x%63;
  const int tid = threadIdx.x;
  const int n = ch*256+tid;
  if (n < TOKB) {
    const int tok = b*TOKB+n;
    float hx[32];
    const float4* src = (const float4*)(hbuf + (size_t)tok*32);
    #pragma unroll
    for (int i=0;i<8;i++){ float4 v4=src[i]; hx[4*i]=v4.x; hx[4*i+1]=v4.y; hx[4*i+2]=v4.z; hx[4*i+3]=v4.w; }
    float mu=0;
    #pragma unroll
    for (int i=0;i<32;i++) mu += hx[i];
    mu *= (1.0f/32.0f);
    float vs=0;
    #pragma unroll
    for (int i=0;i<32;i++){ float d=hx[i]-mu; vs += d*d; }
    const float inv = rsqrtf(vs*(1.0f/32.0f)+EPS);
    const float w = __expf(s[tok]-bmax[b]);
    #pragma unroll
    for (int i=0;i<32;i++) red[tid][i] = w*((hx[i]-mu)*inv*ng[i]+nb[i]);
  } else {
    #pragma unroll
    for (int i=0;i<32;i++) red[tid][i]=0.0f;
  }
  __syncthreads();
  if (tid<32){
    float acc=0.0f;
    for (int t=0;t<256;t++) acc += red[t][tid];
    pp[(size_t)blockIdx.x*32 + tid] = acc;
  }
}

__global__ __launch_bounds__(64) void k_pool_final(
    const float* __restrict__ pp, const float* __restrict__ bsum,
    const float* __restrict__ fcw, const float* __restrict__ fcb,
    float* __restrict__ out)
{
  __shared__ float sp[32];
  const int b = blockIdx.x, tid = threadIdx.x;
  if (tid<32){
    float acc=0.0f;
    for (int ch=0;ch<63;ch++) acc += pp[(size_t)(b*63+ch)*32+tid];
    sp[tid] = acc / bsum[b];
  }
  __syncthreads();
  if (tid<2){
    float v = fcb[tid];
    for (int o=0;o<32;o++) v += sp[o]*fcw[o*2+tid];
    out[b*2+tid]=v;
  }
}

extern "C" void kernel_launch(void* const* d_in, const int* in_sizes, int n_in,
                              void* d_out, int out_size, void* d_ws, size_t ws_size,
                              hipStream_t stream)
{
  const float* x      = (const float*)d_in[0];
  const float* band_w = (const float*)d_in[1];
  const float* pw_w   = (const float*)d_in[2];
  const float* bn_g   = (const float*)d_in[3];
  const float* bn_b   = (const float*)d_in[4];
  const float* bn_m   = (const float*)d_in[5];
  const float* bn_v   = (const float*)d_in[6];
  const float* ln1_g  = (const float*)d_in[7];
  const float* ln1_b  = (const float*)d_in[8];
  const float* wqkv   = (const float*)d_in[9];
  const float* proj   = (const float*)d_in[10];
  const float* wproj  = (const float*)d_in[11];
  const float* bprojp = (const float*)d_in[12];
  const float* ln2_g  = (const float*)d_in[13];
  const float* ln2_b  = (const float*)d_in[14];
  const float* w1     = (const float*)d_in[15];
  const float* b1     = (const float*)d_in[16];
  const float* w2     = (const float*)d_in[17];
  const float* b2     = (const float*)d_in[18];
  const float* norm_g = (const float*)d_in[19];
  const float* norm_b = (const float*)d_in[20];
  const float* pool_w = (const float*)d_in[21];
  const float* pool_b = (const float*)d_in[22];
  const float* fc_w   = (const float*)d_in[23];
  const float* fc_b   = (const float*)d_in[24];
  float* out = (float*)d_out;
  float* ws  = (float*)d_ws;

  float* hbuf  = ws;                       // 8,192,000 floats (32 MB)
  float* kvp   = hbuf + 8192000;           // 2000*2048 = 4,096,000
  float* p2    = kvp  + 4096000;           // 10*2048 = 20,480
  float* KV    = p2   + 20480;             // 2048
  float* sbuf  = KV   + 2048;              // 256,000
  float* bmax  = sbuf + 256000;            // 16
  float* bsum  = bmax + 16;                // 16
  float* pp    = bsum + 16;                // 16*63*32 = 32,256

  k_tokenize<<<1024,256,0,stream>>>(x, band_w, pw_w, bn_g, bn_b, bn_m, bn_v, hbuf);
  for (int l=0;l<2;l++){
    k_kv_partial<<<2000,256,0,stream>>>(hbuf, ln1_g, ln1_b, wqkv, proj, kvp, l);
    k_kv_reduce1<<<80,256,0,stream>>>(kvp, p2);
    k_kv_reduce2<<<1,256,0,stream>>>(p2, KV);
    k_attn<<<8000,256,0,stream>>>(hbuf, ln1_g, ln1_b, wqkv, proj, wproj, bprojp, KV, l);
    k_ffn<<<8000,256,0,stream>>>(hbuf, ln2_g, ln2_b, w1, b1, w2, b2, l);
  }
  k_pool_score<<<1000,256,0,stream>>>(hbuf, norm_g, norm_b, pool_w, pool_b, sbuf);
  k_softmax_stats<<<16,256,0,stream>>>(sbuf, bmax, bsum);
  k_pool_partial<<<16*63,256,0,stream>>>(hbuf, norm_g, norm_b, sbuf, bmax, pp);
  k_pool_final<<<16,64,0,stream>>>(pp, bsum, fc_w, fc_b, out);
}

// Round 7
// 627.878 us; speedup vs baseline: 3.0187x; 1.2931x over previous
//
#include <hip/hip_runtime.h>
#include <math.h>

#define NTOK   256000
#define TOKB   16000
#define EPS    1e-5f

__device__ __forceinline__ float gelu_f(float x){
  return 0.5f*x*(1.0f+erff(x*0.70710678118654752440f));
}
__device__ __forceinline__ float elu1_f(float x){
  return x>0.0f ? x+1.0f : __expf(x);   // elu(x)+1
}

// ---------------------------------------------------------------------------
// Tokenizer: band conv(51) -> 1x1 conv(4->32) -> BN -> GELU -> avgpool(4)
// ---------------------------------------------------------------------------
__global__ __launch_bounds__(256) void k_tokenize(
    const float* __restrict__ x, const float* __restrict__ band_w,
    const float* __restrict__ pw_w, const float* __restrict__ bn_g,
    const float* __restrict__ bn_b, const float* __restrict__ bn_m,
    const float* __restrict__ bn_v, float* __restrict__ hout)
{
  __shared__ float sx[1050];
  __shared__ float sbw[4][51];
  __shared__ float spw[32][4];
  __shared__ float sscale[32], sshift[32];
  const int tid = threadIdx.x;
  const int b = blockIdx.x >> 6, e = blockIdx.x & 63;
  const float* xr = x + (size_t)(b*64 + e)*1000;
  for (int i=tid;i<1050;i+=256){ int t=i-25; sx[i]=(t>=0&&t<1000)?xr[t]:0.0f; }
  for (int i=tid;i<204;i+=256){ sbw[i/51][i%51] = band_w[i]; }
  for (int i=tid;i<128;i+=256){ spw[i>>2][i&3] = pw_w[i]; }
  if (tid<32){ float sc = bn_g[tid]*rsqrtf(bn_v[tid]+EPS);
               sscale[tid]=sc; sshift[tid]=bn_b[tid]-bn_m[tid]*sc; }
  __syncthreads();
  const int tp = tid;
  if (tp < 250) {
    float acc[32];
    #pragma unroll
    for (int o=0;o<32;o++) acc[o]=0.0f;
    for (int j=0;j<4;j++){
      const int t = 4*tp+j;
      float c0=0,c1=0,c2=0,c3=0;
      for (int k=0;k<51;k++){
        float xv = sx[t+k];
        c0 += xv*sbw[0][k]; c1 += xv*sbw[1][k];
        c2 += xv*sbw[2][k]; c3 += xv*sbw[3][k];
      }
      #pragma unroll
      for (int o=0;o<32;o++){
        float hv = spw[o][0]*c0 + spw[o][1]*c1 + spw[o][2]*c2 + spw[o][3]*c3;
        hv = hv*sscale[o] + sshift[o];
        acc[o] += gelu_f(hv);
      }
    }
    const int tok = b*TOKB + e*250 + tp;
    float4* dst = (float4*)(hout + (size_t)tok*32);
    #pragma unroll
    for (int o8=0;o8<8;o8++)
      dst[o8] = make_float4(acc[o8*4]*0.25f, acc[o8*4+1]*0.25f,
                            acc[o8*4+2]*0.25f, acc[o8*4+3]*0.25f);
  }
}

// ---------------------------------------------------------------------------
// Pass A: per 128-token tile: ln1 -> k,v -> K-features -> partial KV[h,f,d]
// ---------------------------------------------------------------------------
__global__ __launch_bounds__(256) void k_kv_partial(
    const float* __restrict__ hbuf, const float* __restrict__ ln1_g,
    const float* __restrict__ ln1_b, const float* __restrict__ wqkv,
    const float* __restrict__ proj_mat, float* __restrict__ kvpart, int l)
{
  __shared__ __align__(16) float sk[128][36];
  __shared__ __align__(16) float sv[128][36];
  __shared__ __align__(16) float swkT[64][32];   // [j][i]: j=0..31 k-cols, 32..63 v-cols
  __shared__ float sg[32], sb[32];
  const int tid = threadIdx.x;
  const float* W = wqkv + l*32*96;
  for (int idx=tid;idx<2048;idx+=256){
    int i = idx&31, j = idx>>5;
    swkT[j][i] = W[i*96 + 32 + j];
  }
  if (tid<32){ sg[tid]=ln1_g[l*32+tid]; sb[tid]=ln1_b[l*32+tid]; }
  __syncthreads();
  {
    const int tloc = tid>>1, half = tid&1;
    const int tok = blockIdx.x*128 + tloc;
    float hx[32];
    const float4* src = (const float4*)(hbuf + (size_t)tok*32);
    #pragma unroll
    for (int i=0;i<8;i++){ float4 v4=src[i]; hx[4*i]=v4.x; hx[4*i+1]=v4.y; hx[4*i+2]=v4.z; hx[4*i+3]=v4.w; }
    float mu=0;
    #pragma unroll
    for (int i=0;i<32;i++) mu += hx[i];
    mu *= (1.0f/32.0f);
    float vs=0;
    #pragma unroll
    for (int i=0;i<32;i++){ float d=hx[i]-mu; vs += d*d; }
    const float inv = rsqrtf(vs*(1.0f/32.0f)+EPS);
    float xn[32];
    #pragma unroll
    for (int i=0;i<32;i++) xn[i] = (hx[i]-mu)*inv*sg[i]+sb[i];
    const int j0 = half*16;
    #pragma unroll 4
    for (int jj=0;jj<16;jj++){
      const int j = j0+jj;
      const float4* wk4 = (const float4*)&swkT[j][0];
      const float4* wv4 = (const float4*)&swkT[32+j][0];
      float ka=0, va=0;
      #pragma unroll
      for (int i4=0;i4<8;i4++){
        float4 wk = wk4[i4], wv = wv4[i4];
        ka += xn[4*i4+0]*wk.x + xn[4*i4+1]*wk.y + xn[4*i4+2]*wk.z + xn[4*i4+3]*wk.w;
        va += xn[4*i4+0]*wv.x + xn[4*i4+1]*wv.y + xn[4*i4+2]*wv.z + xn[4*i4+3]*wv.w;
      }
      sk[tloc][j]=ka; sv[tloc][j]=va;
    }
  }
  __syncthreads();
  const int hh = tid>>6, f = tid&63;
  float pm0,pm1,pm2,pm3,pm4,pm5,pm6,pm7;
  {
    const float* pmp = proj_mat + ((size_t)(l*4+hh)*8)*64 + f;
    pm0=pmp[0]; pm1=pmp[64]; pm2=pmp[128]; pm3=pmp[192];
    pm4=pmp[256]; pm5=pmp[320]; pm6=pmp[384]; pm7=pmp[448];
  }
  float a0=0,a1=0,a2=0,a3=0,a4=0,a5=0,a6=0,a7=0;
  #pragma unroll 4
  for (int t=0;t<128;t++){
    const float4* k4 = (const float4*)&sk[t][hh*8];
    const float4* v4 = (const float4*)&sv[t][hh*8];
    float4 ka = k4[0], kb = k4[1];
    float kd = ka.x*pm0 + ka.y*pm1 + ka.z*pm2 + ka.w*pm3
             + kb.x*pm4 + kb.y*pm5 + kb.z*pm6 + kb.w*pm7;
    const float Kf = elu1_f(kd);
    float4 va = v4[0], vb = v4[1];
    a0 += Kf*va.x; a1 += Kf*va.y; a2 += Kf*va.z; a3 += Kf*va.w;
    a4 += Kf*vb.x; a5 += Kf*vb.y; a6 += Kf*vb.z; a7 += Kf*vb.w;
  }
  float4* dst = (float4*)(kvpart + (size_t)blockIdx.x*2048 + tid*8);
  dst[0] = make_float4(a0,a1,a2,a3);
  dst[1] = make_float4(a4,a5,a6,a7);
}

// fixed-order hierarchical KV reduction: 2000 partials -> 10 chunks -> final
__global__ __launch_bounds__(256) void k_kv_reduce1(
    const float* __restrict__ kvpart, float* __restrict__ p2)
{
  const int chunk = blockIdx.x >> 3;                 // 0..9
  const int e = (blockIdx.x&7)*256 + threadIdx.x;    // 0..2047
  float acc=0.0f;
  const int base = chunk*200;
  for (int ab=0; ab<200; ab++) acc += kvpart[(size_t)(base+ab)*2048 + e];
  p2[chunk*2048 + e] = acc;
}

__global__ __launch_bounds__(256) void k_kv_reduce2(
    const float* __restrict__ p2, float* __restrict__ KV)
{
  const int hf = threadIdx.x;
  float acc[8];
  #pragma unroll
  for (int d=0;d<8;d++) acc[d]=0.0f;
  for (int c=0;c<10;c++){
    #pragma unroll
    for (int d=0;d<8;d++) acc[d] += p2[c*2048 + hf*8 + d];
  }
  #pragma unroll
  for (int d=0;d<8;d++) KV[hf*8+d]=acc[d];
}

// ---------------------------------------------------------------------------
// Pass C1 (thread-per-token): ln1 -> per-head q,Qfeat,attn -> proj+residual.
// All LDS weight reads are WAVE-UNIFORM (broadcast): one DS op serves 64
// tokens. No shuffles, no barriers in hot path. No register array is
// indexed by a runtime loop variable (rule #20).
// ---------------------------------------------------------------------------
__global__ __launch_bounds__(256) void k_attn(
    float* __restrict__ hbuf,
    const float* __restrict__ ln1_g, const float* __restrict__ ln1_b,
    const float* __restrict__ wqkv, const float* __restrict__ proj_mat,
    const float* __restrict__ wproj, const float* __restrict__ bproj,
    const float* __restrict__ KV, int l)
{
  __shared__ __align__(16) float swqT[32][32];     // [j][i] = wqkv[i][j]
  __shared__ __align__(16) float pmT[4][64][8];    // [h][f][d]
  __shared__ __align__(16) float kvT[4][64][8];    // [h][f][d]
  __shared__ __align__(16) float wpT[32][32];      // [o][i] = wproj[i][o]
  __shared__ float s1g[32],s1b[32],sbp[32];
  const int tid = threadIdx.x;
  for (int idx=tid;idx<1024;idx+=256){
    int j=idx>>5, i=idx&31;
    swqT[j][i] = wqkv[l*3072 + i*96 + j];
    wpT[j][i]  = wproj[l*1024 + i*32 + j];
  }
  for (int idx=tid;idx<2048;idx+=256){
    int hh=idx>>9, f=(idx>>3)&63, d=idx&7;
    pmT[hh][f][d] = proj_mat[l*2048 + hh*512 + d*64 + f];
    (&kvT[0][0][0])[idx] = KV[idx];
  }
  if (tid<32){ s1g[tid]=ln1_g[l*32+tid]; s1b[tid]=ln1_b[l*32+tid];
               sbp[tid]=bproj[l*32+tid]; }
  __syncthreads();

  const int tok = blockIdx.x*256 + tid;
  float4* hp = (float4*)(hbuf + (size_t)tok*32);

  // ---- load h, ln1 (lane-local) ----
  float xn[32];
  {
    float hx[32];
    #pragma unroll
    for (int i=0;i<8;i++){ float4 v=hp[i]; hx[4*i]=v.x; hx[4*i+1]=v.y; hx[4*i+2]=v.z; hx[4*i+3]=v.w; }
    float mu=0;
    #pragma unroll
    for (int i=0;i<32;i++) mu += hx[i];
    mu *= (1.0f/32.0f);
    float vs=0;
    #pragma unroll
    for (int i=0;i<32;i++){ float d=hx[i]-mu; vs += d*d; }
    const float inv = rsqrtf(vs*(1.0f/32.0f)+EPS);
    #pragma unroll
    for (int i=0;i<32;i++) xn[i] = (hx[i]-mu)*inv*s1g[i]+s1b[i];
  }

  // ---- per-head: q slice -> Qfeat stream -> normalized att ----
  float att[32];
  #pragma unroll
  for (int hh=0;hh<4;hh++){
    float qh[8];
    #pragma unroll
    for (int d=0;d<8;d++){
      const float4* wr = (const float4*)&swqT[hh*8+d][0];
      float a=0;
      #pragma unroll
      for (int i4=0;i4<8;i4++){
        float4 w = wr[i4];
        a += xn[4*i4+0]*w.x + xn[4*i4+1]*w.y + xn[4*i4+2]*w.z + xn[4*i4+3]*w.w;
      }
      qh[d]=a;
    }
    float ao[8];
    #pragma unroll
    for (int d=0;d<8;d++) ao[d]=0.0f;
    for (int f=0;f<64;f++){
      const float4* pm4 = (const float4*)&pmT[hh][f][0];
      float4 pa = pm4[0], pb = pm4[1];
      float qd = qh[0]*pa.x+qh[1]*pa.y+qh[2]*pa.z+qh[3]*pa.w
               + qh[4]*pb.x+qh[5]*pb.y+qh[6]*pb.z+qh[7]*pb.w;
      const float Qf = elu1_f(qd);
      const float4* kv4 = (const float4*)&kvT[hh][f][0];
      float4 va = kv4[0], vb = kv4[1];
      ao[0] += Qf*va.x; ao[1] += Qf*va.y; ao[2] += Qf*va.z; ao[3] += Qf*va.w;
      ao[4] += Qf*vb.x; ao[5] += Qf*vb.y; ao[6] += Qf*vb.z; ao[7] += Qf*vb.w;
    }
    const float den = ao[0]+ao[1]+ao[2]+ao[3]+ao[4]+ao[5]+ao[6]+ao[7];
    const float z = 1.0f/den;
    #pragma unroll
    for (int d=0;d<8;d++) att[hh*8+d] = ao[d]*z;
  }

  // ---- proj + residual, streamed in float4 output chunks ----
  const float4* sbp4 = (const float4*)sbp;
  for (int o4=0;o4<8;o4++){
    float4 bb = sbp4[o4];
    float p0=bb.x, p1=bb.y, p2=bb.z, p3=bb.w;
    const float4* w0 = (const float4*)&wpT[o4*4+0][0];
    const float4* w1r= (const float4*)&wpT[o4*4+1][0];
    const float4* w2r= (const float4*)&wpT[o4*4+2][0];
    const float4* w3 = (const float4*)&wpT[o4*4+3][0];
    #pragma unroll
    for (int i4=0;i4<8;i4++){
      float4 a0=w0[i4], a1=w1r[i4], a2=w2r[i4], a3=w3[i4];
      p0 += att[4*i4+0]*a0.x + att[4*i4+1]*a0.y + att[4*i4+2]*a0.z + att[4*i4+3]*a0.w;
      p1 += att[4*i4+0]*a1.x + att[4*i4+1]*a1.y + att[4*i4+2]*a1.z + att[4*i4+3]*a1.w;
      p2 += att[4*i4+0]*a2.x + att[4*i4+1]*a2.y + att[4*i4+2]*a2.z + att[4*i4+3]*a2.w;
      p3 += att[4*i4+0]*a3.x + att[4*i4+1]*a3.y + att[4*i4+2]*a3.z + att[4*i4+3]*a3.w;
    }
    float4 hx4 = hp[o4];
    hp[o4] = make_float4(hx4.x+p0, hx4.y+p1, hx4.z+p2, hx4.w+p3);
  }
}

// ---------------------------------------------------------------------------
// Pass C2 (thread-per-token): ln2 -> FFN(gelu) -> residual. g_j is consumed
// immediately (never stored); weight reads wave-uniform broadcast.
// ---------------------------------------------------------------------------
__global__ __launch_bounds__(256) void k_ffn(
    float* __restrict__ hbuf,
    const float* __restrict__ ln2_g, const float* __restrict__ ln2_b,
    const float* __restrict__ w1, const float* __restrict__ b1,
    const float* __restrict__ w2, const float* __restrict__ b2, int l)
{
  __shared__ __align__(16) float w1T[64][32];   // [j][i] = w1[i][j]
  __shared__ __align__(16) float sw2[64][32];   // [j][c] = w2[j][c]
  __shared__ float s2g[32],s2b[32],sb1[64],sb2[32];
  const int tid = threadIdx.x;
  for (int idx=tid;idx<2048;idx+=256){
    int j=idx>>5, i=idx&31;
    w1T[j][i] = w1[l*2048 + i*64 + j];
    (&sw2[0][0])[idx] = w2[l*2048 + idx];
  }
  if (tid<32){ s2g[tid]=ln2_g[l*32+tid]; s2b[tid]=ln2_b[l*32+tid];
               sb2[tid]=b2[l*32+tid]; }
  if (tid<64) sb1[tid]=b1[l*64+tid];
  __syncthreads();

  const int tok = blockIdx.x*256 + tid;
  float4* hp = (float4*)(hbuf + (size_t)tok*32);

  // ---- load h, ln2 (lane-local) ----
  float m[32];
  {
    float hx[32];
    #pragma unroll
    for (int i=0;i<8;i++){ float4 v=hp[i]; hx[4*i]=v.x; hx[4*i+1]=v.y; hx[4*i+2]=v.z; hx[4*i+3]=v.w; }
    float mu=0;
    #pragma unroll
    for (int i=0;i<32;i++) mu += hx[i];
    mu *= (1.0f/32.0f);
    float vs=0;
    #pragma unroll
    for (int i=0;i<32;i++){ float d=hx[i]-mu; vs += d*d; }
    const float inv = rsqrtf(vs*(1.0f/32.0f)+EPS);
    #pragma unroll
    for (int i=0;i<32;i++) m[i] = (hx[i]-mu)*inv*s2g[i]+s2b[i];
  }

  // ---- FFN accumulators ----
  float f[32];
  const float4* sb24 = (const float4*)sb2;
  #pragma unroll
  for (int c4=0;c4<8;c4++){
    float4 b = sb24[c4];
    f[4*c4+0]=b.x; f[4*c4+1]=b.y; f[4*c4+2]=b.z; f[4*c4+3]=b.w;
  }

  // ---- stream j: g_j -> gelu -> accumulate into f ----
  for (int j=0;j<64;j++){
    const float4* w1r = (const float4*)&w1T[j][0];
    float g = sb1[j];
    #pragma unroll
    for (int i4=0;i4<8;i4++){
      float4 w = w1r[i4];
      g += m[4*i4+0]*w.x + m[4*i4+1]*w.y + m[4*i4+2]*w.z + m[4*i4+3]*w.w;
    }
    const float gg = gelu_f(g);
    const float4* w2r = (const float4*)&sw2[j][0];
    #pragma unroll
    for (int c4=0;c4<8;c4++){
      float4 w = w2r[c4];
      f[4*c4+0] += gg*w.x; f[4*c4+1] += gg*w.y;
      f[4*c4+2] += gg*w.z; f[4*c4+3] += gg*w.w;
    }
  }

  // ---- residual (fully unrolled: f statically indexed) ----
  #pragma unroll
  for (int o4=0;o4<8;o4++){
    float4 hx4 = hp[o4];
    hp[o4] = make_float4(hx4.x+f[4*o4+0], hx4.y+f[4*o4+1],
                         hx4.z+f[4*o4+2], hx4.w+f[4*o4+3]);
  }
}

// ---------------------------------------------------------------------------
// Final: layernorm -> pool score s; softmax over N per batch; weighted sum; fc
// ---------------------------------------------------------------------------
__global__ __launch_bounds__(256) void k_pool_score(
    const float* __restrict__ hbuf, const float* __restrict__ ng,
    const float* __restrict__ nb, const float* __restrict__ pw,
    const float* __restrict__ pb, float* __restrict__ s)
{
  const int tok = blockIdx.x*256 + threadIdx.x;
  float hx[32];
  const float4* src = (const float4*)(hbuf + (size_t)tok*32);
  #pragma unroll
  for (int i=0;i<8;i++){ float4 v4=src[i]; hx[4*i]=v4.x; hx[4*i+1]=v4.y; hx[4*i+2]=v4.z; hx[4*i+3]=v4.w; }
  float mu=0;
  #pragma unroll
  for (int i=0;i<32;i++) mu += hx[i];
  mu *= (1.0f/32.0f);
  float vs=0;
  #pragma unroll
  for (int i=0;i<32;i++){ float d=hx[i]-mu; vs += d*d; }
  const float inv = rsqrtf(vs*(1.0f/32.0f)+EPS);
  float sv = pb[0];
  #pragma unroll
  for (int i=0;i<32;i++) sv += ((hx[i]-mu)*inv*ng[i]+nb[i])*pw[i];
  s[tok]=sv;
}

__global__ __launch_bounds__(256) void k_softmax_stats(
    const float* __restrict__ s, float* __restrict__ bmax, float* __restrict__ bsum)
{
  __shared__ float red[256];
  __shared__ float smax_sh;
  const int b = blockIdx.x, tid = threadIdx.x;
  const float* sbp = s + (size_t)b*TOKB;
  float mx = -INFINITY;
  for (int i=tid;i<TOKB;i+=256) mx = fmaxf(mx, sbp[i]);
  red[tid]=mx; __syncthreads();
  for (int st=128;st>0;st>>=1){ if(tid<st) red[tid]=fmaxf(red[tid],red[tid+st]); __syncthreads(); }
  if (tid==0) smax_sh = red[0];
  __syncthreads();
  const float smax = smax_sh;
  float acc=0.0f;
  for (int i=tid;i<TOKB;i+=256) acc += __expf(sbp[i]-smax);
  __syncthreads();
  red[tid]=acc; __syncthreads();
  for (int st=128;st>0;st>>=1){ if(tid<st) red[tid]+=red[tid+st]; __syncthreads(); }
  if (tid==0){ bmax[b]=smax; bsum[b]=red[0]; }
}

__global__ __launch_bounds__(256) void k_pool_partial(
    const float* __restrict__ hbuf, const float* __restrict__ ng,
    const float* __restrict__ nb, const float* __restrict__ s,
    const float* __restrict__ bmax, float* __restrict__ pp)
{
  __shared__ float red[256][33];
  const int b = blockIdx.x/63, ch = blockIdx.x%63;
  const int tid = threadIdx.x;
  const int n = ch*256+tid;
  if (n < TOKB) {
    const int tok = b*TOKB+n;
    float hx[32];
    const float4* src = (const float4*)(hbuf + (size_t)tok*32);
    #pragma unroll
    for (int i=0;i<8;i++){ float4 v4=src[i]; hx[4*i]=v4.x; hx[4*i+1]=v4.y; hx[4*i+2]=v4.z; hx[4*i+3]=v4.w; }
    float mu=0;
    #pragma unroll
    for (int i=0;i<32;i++) mu += hx[i];
    mu *= (1.0f/32.0f);
    float vs=0;
    #pragma unroll
    for (int i=0;i<32;i++){ float d=hx[i]-mu; vs += d*d; }
    const float inv = rsqrtf(vs*(1.0f/32.0f)+EPS);
    const float w = __expf(s[tok]-bmax[b]);
    #pragma unroll
    for (int i=0;i<32;i++) red[tid][i] = w*((hx[i]-mu)*inv*ng[i]+nb[i]);
  } else {
    #pragma unroll
    for (int i=0;i<32;i++) red[tid][i]=0.0f;
  }
  __syncthreads();
  if (tid<32){
    float acc=0.0f;
    for (int t=0;t<256;t++) acc += red[t][tid];
    pp[(size_t)blockIdx.x*32 + tid] = acc;
  }
}

__global__ __launch_bounds__(64) void k_pool_final(
    const float* __restrict__ pp, const float* __restrict__ bsum,
    const float* __restrict__ fcw, const float* __restrict__ fcb,
    float* __restrict__ out)
{
  __shared__ float sp[32];
  const int b = blockIdx.x, tid = threadIdx.x;
  if (tid<32){
    float acc=0.0f;
    for (int ch=0;ch<63;ch++) acc += pp[(size_t)(b*63+ch)*32+tid];
    sp[tid] = acc / bsum[b];
  }
  __syncthreads();
  if (tid<2){
    float v = fcb[tid];
    for (int o=0;o<32;o++) v += sp[o]*fcw[o*2+tid];
    out[b*2+tid]=v;
  }
}

extern "C" void kernel_launch(void* const* d_in, const int* in_sizes, int n_in,
                              void* d_out, int out_size, void* d_ws, size_t ws_size,
                              hipStream_t stream)
{
  const float* x      = (const float*)d_in[0];
  const float* band_w = (const float*)d_in[1];
  const float* pw_w   = (const float*)d_in[2];
  const float* bn_g   = (const float*)d_in[3];
  const float* bn_b   = (const float*)d_in[4];
  const float* bn_m   = (const float*)d_in[5];
  const float* bn_v   = (const float*)d_in[6];
  const float* ln1_g  = (const float*)d_in[7];
  const float* ln1_b  = (const float*)d_in[8];
  const float* wqkv   = (const float*)d_in[9];
  const float* proj   = (const float*)d_in[10];
  const float* wproj  = (const float*)d_in[11];
  const float* bprojp = (const float*)d_in[12];
  const float* ln2_g  = (const float*)d_in[13];
  const float* ln2_b  = (const float*)d_in[14];
  const float* w1     = (const float*)d_in[15];
  const float* b1     = (const float*)d_in[16];
  const float* w2     = (const float*)d_in[17];
  const float* b2     = (const float*)d_in[18];
  const float* norm_g = (const float*)d_in[19];
  const float* norm_b = (const float*)d_in[20];
  const float* pool_w = (const float*)d_in[21];
  const float* pool_b = (const float*)d_in[22];
  const float* fc_w   = (const float*)d_in[23];
  const float* fc_b   = (const float*)d_in[24];
  float* out = (float*)d_out;
  float* ws  = (float*)d_ws;

  float* hbuf  = ws;                       // 8,192,000 floats (32 MB)
  float* kvp   = hbuf + 8192000;           // 2000*2048 = 4,096,000
  float* p2    = kvp  + 4096000;           // 10*2048 = 20,480
  float* KV    = p2   + 20480;             // 2048
  float* sbuf  = KV   + 2048;              // 256,000
  float* bmax  = sbuf + 256000;            // 16
  float* bsum  = bmax + 16;                // 16
  float* pp    = bsum + 16;                // 16*63*32 = 32,256

  k_tokenize<<<1024,256,0,stream>>>(x, band_w, pw_w, bn_g, bn_b, bn_m, bn_v, hbuf);
  for (int l=0;l<2;l++){
    k_kv_partial<<<2000,256,0,stream>>>(hbuf, ln1_g, ln1_b, wqkv, proj, kvp, l);
    k_kv_reduce1<<<80,256,0,stream>>>(kvp, p2);
    k_kv_reduce2<<<1,256,0,stream>>>(p2, KV);
    k_attn<<<1000,256,0,stream>>>(hbuf, ln1_g, ln1_b, wqkv, proj, wproj, bprojp, KV, l);
    k_ffn<<<1000,256,0,stream>>>(hbuf, ln2_g, ln2_b, w1, b1, w2, b2, l);
  }
  k_pool_score<<<1000,256,0,stream>>>(hbuf, norm_g, norm_b, pool_w, pool_b, sbuf);
  k_softmax_stats<<<16,256,0,stream>>>(sbuf, bmax, bsum);
  k_pool_partial<<<16*63,256,0,stream>>>(hbuf, norm_g, norm_b, sbuf, bmax, pp);
  k_pool_final<<<16,64,0,stream>>>(pp, bsum, fc_w, fc_b, out);
}